// Round 13
// baseline (154.096 us; speedup 1.0000x reference)
//
#include <hip/hip_runtime.h>

typedef __bf16 bf16;
typedef __bf16 bf16x8 __attribute__((ext_vector_type(8)));
typedef __bf16 bf16x4 __attribute__((ext_vector_type(4)));
typedef float  f32x4  __attribute__((ext_vector_type(4)));
typedef float  f32x16 __attribute__((ext_vector_type(16)));
typedef unsigned int u32;
typedef u32 u32x4 __attribute__((ext_vector_type(4)));

#define AS1U(p) ((const __attribute__((address_space(1))) unsigned int*)(p))
#define AS3U(p) ((__attribute__((address_space(3))) unsigned int*)(p))

static __device__ __forceinline__ u32 pack2(float a, float b) {
    unsigned short ua = __builtin_bit_cast(unsigned short, (bf16)a);
    unsigned short ub = __builtin_bit_cast(unsigned short, (bf16)b);
    return (u32)ua | ((u32)ub << 16);
}

// ---------------- fused: LayerNorm (blocks 0..4095) + 4x W transpose --------
__global__ void prep_kernel(const float* __restrict__ q,
                            const float* __restrict__ gamma,
                            const float* __restrict__ beta,
                            bf16* __restrict__ h,
                            const float* __restrict__ W0, const float* __restrict__ W1,
                            const float* __restrict__ W2, const float* __restrict__ W3,
                            bf16* __restrict__ D0, bf16* __restrict__ D1,
                            bf16* __restrict__ D2, bf16* __restrict__ D3) {
    __shared__ float tile[32][33];
    __shared__ float ssum[4], ssum2[4];
    const int blk = blockIdx.x;
    const int t = threadIdx.x;  // 256
    if (blk < 4096) {
        const float* xr = q + (size_t)blk * 1024;
        float4 v = ((const float4*)xr)[t];
        float s  = v.x + v.y + v.z + v.w;
        float s2 = v.x * v.x + v.y * v.y + v.z * v.z + v.w * v.w;
#pragma unroll
        for (int m = 1; m < 64; m <<= 1) {
            s  += __shfl_xor(s, m, 64);
            s2 += __shfl_xor(s2, m, 64);
        }
        const int wid = t >> 6, lane = t & 63;
        if (lane == 0) { ssum[wid] = s; ssum2[wid] = s2; }
        __syncthreads();
        s  = ssum[0] + ssum[1] + ssum[2] + ssum[3];
        s2 = ssum2[0] + ssum2[1] + ssum2[2] + ssum2[3];
        const float mu  = s * (1.f / 1024.f);
        const float var = s2 * (1.f / 1024.f) - mu * mu;
        const float rs  = rsqrtf(var + 1e-5f);
        float4 g = ((const float4*)gamma)[t];
        float4 b = ((const float4*)beta)[t];
        bf16x4 o;
        o[0] = (bf16)((v.x - mu) * rs * g.x + b.x);
        o[1] = (bf16)((v.y - mu) * rs * g.y + b.y);
        o[2] = (bf16)((v.z - mu) * rs * g.z + b.z);
        o[3] = (bf16)((v.w - mu) * rs * g.w + b.w);
        ((bf16x4*)(h + (size_t)blk * 1024))[t] = o;
    } else {
        const int z = blk - 4096;
        const float* W; bf16* D;
        switch (z >> 10) {
            case 0: W = W0; D = D0; break;
            case 1: W = W1; D = D1; break;
            case 2: W = W2; D = D2; break;
            default: W = W3; D = D3; break;
        }
        const int bi = (z & 1023) >> 5, bj = z & 31;
        const int tx = t & 31, ty = t >> 5;  // 32 x 8
#pragma unroll
        for (int i = 0; i < 4; i++) {
            tile[ty + i * 8][tx] = W[(size_t)(bi * 32 + ty + i * 8) * 1024 + bj * 32 + tx];
        }
        __syncthreads();
#pragma unroll
        for (int i = 0; i < 4; i++) {
            D[(size_t)(bj * 32 + ty + i * 8) * 1024 + bi * 32 + tx] =
                (bf16)tile[tx][ty + i * 8];
        }
    }
}

// ---------------- GEMM0: qkv = h @ WcatT^T, 256x256 tile, BK=32 -------------
// Phase-split schedule (T3+T4): 2 phases/K-tile, counted vmcnt(2) at every
// tile boundary (loads for future tiles stay in flight across barriers).
// Staging skew: ph0 stages A(T+1)->buf^1; ph1 stages B(T+2)->cur B region
// (B was consumed into registers at ph0). XOR-swizzled LDS both-sides.
// Epilogue: per-wave LDS coalescing (two 64-row passes), Q scale folded,
// V relu + transpose into Vt.
__global__ __launch_bounds__(512, 2)
void gemm0_kernel(const bf16* __restrict__ A, const bf16* __restrict__ BT,
                  bf16* __restrict__ Cb,
                  const float* __restrict__ b0, const float* __restrict__ b1,
                  const float* __restrict__ b2, bf16* __restrict__ Vt) {
    __shared__ char lds[65536];  // A: 2buf x 16KB @0 ; B: 2buf x 16KB @32768
    const int tid = threadIdx.x;
    const int lane = tid & 63, wave = tid >> 6;   // 8 waves
    const int wr = wave >> 2, wc = wave & 3;      // 2 (M) x 4 (N)
    const int row16 = lane & 15, g = lane >> 4;
    // grid 12(N) x 16(M); bijective XCD swizzle (192 % 8 == 0)
    const int bid0 = blockIdx.y * 12 + blockIdx.x;
    const int bid = (bid0 & 7) * 24 + (bid0 >> 3);
    const int tileN = (bid % 12) * 256;
    const int tileM = (bid / 12) * 256;

    auto stageA = [&](int T) {  // both halves of A-tile T -> bufA[T&1]
        char* dst = lds + (T & 1) * 16384;
        const size_t colb = (size_t)T * 64;
#pragma unroll
        for (int hf = 0; hf < 2; hf++) {
            const int row = hf * 128 + (tid >> 2);
            const char* src = (const char*)A + (size_t)(tileM + row) * 2048 + colb
                              + (((tid & 3) * 16) ^ ((row & 3) << 4));
            __builtin_amdgcn_global_load_lds(AS1U(src), AS3U(dst + hf * 8192 + tid * 16), 16, 0, 0);
        }
    };
    auto stageB = [&](int T) {
        char* dst = lds + 32768 + (T & 1) * 16384;
        const size_t colb = (size_t)T * 64;
#pragma unroll
        for (int hf = 0; hf < 2; hf++) {
            const int row = hf * 128 + (tid >> 2);
            const char* src = (const char*)BT + (size_t)(tileN + row) * 2048 + colb
                              + (((tid & 3) * 16) ^ ((row & 3) << 4));
            __builtin_amdgcn_global_load_lds(AS1U(src), AS3U(dst + hf * 8192 + tid * 16), 16, 0, 0);
        }
    };

    f32x4 acc[8][4] = {};
    stageA(0); stageB(0); stageB(1);

#pragma unroll 1
    for (int T = 0; T < 32; ++T) {
        if (T == 31) { asm volatile("s_waitcnt vmcnt(0)" ::: "memory"); }
        else         { asm volatile("s_waitcnt vmcnt(2)" ::: "memory"); }
        __builtin_amdgcn_s_barrier();
        asm volatile("" ::: "memory");
        const char* Ab = lds + (T & 1) * 16384;
        const char* Bb = lds + 32768 + (T & 1) * 16384;
        // ---- phase 0: load B-frags (kept in regs for both phases) + A m0..3
        bf16x8 bfr[4];
#pragma unroll
        for (int n = 0; n < 4; n++) {
            const int b_r = wc * 64 + n * 16 + row16;
            bfr[n] = *(const bf16x8*)(Bb + b_r * 64 + ((g * 16) ^ ((b_r & 3) << 4)));
        }
        bf16x8 af[4];
#pragma unroll
        for (int m = 0; m < 4; m++) {
            const int a_r = wr * 128 + m * 16 + row16;
            af[m] = *(const bf16x8*)(Ab + a_r * 64 + ((g * 16) ^ ((a_r & 3) << 4)));
        }
        if (T < 31) stageA(T + 1);
        __builtin_amdgcn_s_barrier();
        asm volatile("s_waitcnt lgkmcnt(0)" ::: "memory");
        __builtin_amdgcn_sched_barrier(0);
        __builtin_amdgcn_s_setprio(1);
#pragma unroll
        for (int m = 0; m < 4; m++)
#pragma unroll
            for (int n = 0; n < 4; n++)
                acc[m][n] = __builtin_amdgcn_mfma_f32_16x16x32_bf16(af[m], bfr[n], acc[m][n], 0, 0, 0);
        __builtin_amdgcn_s_setprio(0);
        __builtin_amdgcn_s_barrier();
        // ---- phase 1: A m4..7 (B(T+2) staged into consumed cur-B region)
#pragma unroll
        for (int m = 0; m < 4; m++) {
            const int a_r = wr * 128 + (m + 4) * 16 + row16;
            af[m] = *(const bf16x8*)(Ab + a_r * 64 + ((g * 16) ^ ((a_r & 3) << 4)));
        }
        if (T < 30) stageB(T + 2);
        __builtin_amdgcn_s_barrier();
        asm volatile("s_waitcnt lgkmcnt(0)" ::: "memory");
        __builtin_amdgcn_sched_barrier(0);
        __builtin_amdgcn_s_setprio(1);
#pragma unroll
        for (int m = 0; m < 4; m++)
#pragma unroll
            for (int n = 0; n < 4; n++)
                acc[m + 4][n] = __builtin_amdgcn_mfma_f32_16x16x32_bf16(af[m], bfr[n], acc[m + 4][n], 0, 0, 0);
        __builtin_amdgcn_s_setprio(0);
        __builtin_amdgcn_s_barrier();
    }

    // ---- epilogue: per-wave 8KB LDS region (overlaid on dead A/B LDS),
    //      two 64-row passes, coalesced bf16x8 stores ----
    char* ep = lds + wave * 8192;  // [64][64] bf16, XOR-swizzled rows
    const bool isV = (tileN >= 2048);
#pragma unroll 1
    for (int pm = 0; pm < 2; pm++) {
        if (!isV) {
#pragma unroll
            for (int n = 0; n < 4; n++) {
                const int cl = n * 16 + row16;
                const int gc = tileN + wc * 64 + cl;
                const float bias = gc < 1024 ? b0[gc] : b1[gc - 1024];
                const float scl = gc < 1024 ? 0.18033688011112042f : 1.f;
#pragma unroll
                for (int m = 0; m < 4; m++)
#pragma unroll
                    for (int j = 0; j < 4; j++) {
                        const int rl = m * 16 + g * 4 + j;
                        const float v = (acc[pm * 4 + m][n][j] + bias) * scl;
                        *(bf16*)(ep + rl * 128 + ((cl * 2) ^ ((rl & 7) << 4))) = (bf16)v;
                    }
            }
        } else {
#pragma unroll
            for (int n = 0; n < 4; n++) {
                const int dl = n * 16 + row16;
                const float bias = b2[(tileN - 2048) + wc * 64 + dl];
#pragma unroll
                for (int m = 0; m < 4; m++)
#pragma unroll
                    for (int j = 0; j < 4; j++) {
                        const int tl = m * 16 + g * 4 + j;
                        const float v = fmaxf(acc[pm * 4 + m][n][j] + bias, 0.f);
                        *(bf16*)(ep + dl * 128 + ((tl * 2) ^ ((dl & 7) << 4))) = (bf16)v;
                    }
            }
        }
        asm volatile("s_waitcnt lgkmcnt(0)" ::: "memory");
        __builtin_amdgcn_sched_barrier(0);
        if (!isV) {
#pragma unroll
            for (int it = 0; it < 8; it++) {
                const int rl = (lane >> 3) + it * 8;
                const bf16x8 vrow = *(const bf16x8*)(ep + rl * 128 +
                                                     (((lane & 7) * 16) ^ ((rl & 7) << 4)));
                const int gr = tileM + wr * 128 + pm * 64 + rl;
                const int gc = tileN + wc * 64 + (lane & 7) * 8;
                *(bf16x8*)&Cb[(size_t)gr * 3072 + gc] = vrow;
            }
        } else {
            const int bb = tileM >> 11;
            const int tbase = (tileM & 2047) + wr * 128 + pm * 64 + (lane & 7) * 8;
#pragma unroll
            for (int it = 0; it < 8; it++) {
                const int dl = (lane >> 3) + it * 8;
                const bf16x8 vrow = *(const bf16x8*)(ep + dl * 128 +
                                                     (((lane & 7) * 16) ^ ((dl & 7) << 4)));
                const int gd = (tileN - 2048) + wc * 64 + dl;
                const int hh = gd >> 6, dd = gd & 63;
                *(bf16x8*)&Vt[(((size_t)bb * 16 + hh) * 64 + dd) * 2048 + tbase] = vrow;
            }
        }
        asm volatile("s_waitcnt lgkmcnt(0)" ::: "memory");
        __builtin_amdgcn_sched_barrier(0);
    }
}

// ---------------- GEMM1: out = Obuf @ WoT^T + bo + resid (fp32) -------------
// 128x128 tile, BK=32, 4 waves; LDS-coalesced float4 epilogue.
__global__ void gemm1_kernel(const bf16* __restrict__ A, const bf16* __restrict__ BT,
                             float* __restrict__ Cf, const float* __restrict__ bo,
                             const float* __restrict__ resid) {
    __shared__ bf16 Asm[128][32];
    __shared__ bf16 Bsm[128][32];
    const int tid = threadIdx.x;
    const int lane = tid & 63, wave = tid >> 6;
    const int wr = wave >> 1, wc = wave & 1;
    const int nwg = gridDim.x * gridDim.y;
    const int bid0 = blockIdx.y * gridDim.x + blockIdx.x;
    const int bid = (bid0 & 7) * (nwg >> 3) + (bid0 >> 3);
    const int tileN = (bid % gridDim.x) * 128;
    const int tileM = (bid / gridDim.x) * 128;
    const int row16 = lane & 15, g = lane >> 4;

    f32x4 acc[4][4] = {};

    for (int kt = 0; kt < 1024; kt += 32) {
#pragma unroll
        for (int i = 0; i < 2; i++) {
            int c = tid + i * 256;
            int r = c >> 2, cb = (c & 3) * 16;
            const char* g_ = (const char*)(A + (size_t)(tileM + r) * 1024 + kt) + cb;
            __builtin_amdgcn_global_load_lds(AS1U(g_), AS3U((char*)&Asm[0][0] + c * 16), 16, 0, 0);
        }
#pragma unroll
        for (int i = 0; i < 2; i++) {
            int c = tid + i * 256;
            int r = c >> 2, cb = (c & 3) * 16;
            const char* g_ = (const char*)(BT + (size_t)(tileN + r) * 1024 + kt) + cb;
            __builtin_amdgcn_global_load_lds(AS1U(g_), AS3U((char*)&Bsm[0][0] + c * 16), 16, 0, 0);
        }
        __syncthreads();
        bf16x8 af[4], bfr[4];
#pragma unroll
        for (int m = 0; m < 4; m++)
            af[m] = *(const bf16x8*)&Asm[wr * 64 + m * 16 + row16][g * 8];
#pragma unroll
        for (int n = 0; n < 4; n++)
            bfr[n] = *(const bf16x8*)&Bsm[wc * 64 + n * 16 + row16][g * 8];
#pragma unroll
        for (int m = 0; m < 4; m++)
#pragma unroll
            for (int n = 0; n < 4; n++)
                acc[m][n] = __builtin_amdgcn_mfma_f32_16x16x32_bf16(af[m], bfr[n],
                                                                   acc[m][n], 0, 0, 0);
        __syncthreads();
    }
    __shared__ float Epf[4][64][66];
    float* ep = &Epf[wave][0][0];
#pragma unroll
    for (int n = 0; n < 4; n++) {
        const int cl = n * 16 + row16;
        const float bias = bo[tileN + wc * 64 + cl];
#pragma unroll
        for (int m = 0; m < 4; m++)
#pragma unroll
            for (int j = 0; j < 4; j++) {
                const int rl = m * 16 + g * 4 + j;
                ep[rl * 66 + cl] = acc[m][n][j] + bias;
            }
    }
    asm volatile("s_waitcnt lgkmcnt(0)" ::: "memory");
    __builtin_amdgcn_sched_barrier(0);
    const int rl0 = lane >> 4;
    const int cl0 = (lane & 15) * 4;
#pragma unroll
    for (int it = 0; it < 16; it++) {
        const int rl = rl0 + it * 4;
        float4 v = *(const float4*)&ep[rl * 66 + cl0];
        const int gr = tileM + wr * 64 + rl;
        const int gc = tileN + wc * 64 + cl0;
        const float4 rv = *(const float4*)&resid[(size_t)gr * 1024 + gc];
        v.x += rv.x; v.y += rv.y; v.z += rv.z; v.w += rv.w;
        *(float4*)&Cf[(size_t)gr * 1024 + gc] = v;
    }
}

// ---------------- flash attention, 32x32 MFMA, in-block KV split ------------
// (unchanged from R12: 512 blocks x 8 waves, ones-MFMA denominator)
__global__ __launch_bounds__(512, 4)
void attn_kernel(const bf16* __restrict__ qkv, const bf16* __restrict__ Vt,
                 bf16* __restrict__ Obuf) {
    const int bid = blockIdx.x;
    const int swz = (bid & 7) * 64 + (bid >> 3);
    const int bh = swz >> 4, qt = swz & 15;
    const int b = bh >> 4, h = bh & 15;
    const int qbase = qt * 128;
    const int tid = threadIdx.x;
    const int lane = tid & 63, wv = tid >> 6;
    const int half = wv >> 2, qw = wv & 3;
    const int c = lane & 31, p = lane >> 5;

    __shared__ bf16 Kl[2][2][64][64];
    __shared__ bf16 Vl[2][2][64][64];

    const bf16* qrow = qkv + (size_t)(b * 2048 + qbase + qw * 32 + c) * 3072 + h * 64;
    bf16x8 qf[4];
#pragma unroll
    for (int ch = 0; ch < 4; ch++)
        qf[ch] = *(const bf16x8*)(qrow + ch * 16 + p * 8);

    const char* kgbase = (const char*)(qkv + (size_t)b * 2048 * 3072 + 1024 + h * 64)
                         + (size_t)(half * 1024) * 6144;
    const char* vgbase = (const char*)(Vt + (size_t)bh * 64 * 2048) + half * 2048;
    const int ht = tid & 255;
    const char* kgp[2]; const char* vgp[2]; int ldo[2];
#pragma unroll
    for (int i = 0; i < 2; i++) {
        const int cc = ht + i * 256;
        const int srow = cc >> 3;
        const int scol = ((cc & 7) * 16) ^ ((srow & 7) << 4);
        kgp[i] = kgbase + (size_t)srow * 6144 + scol;
        vgp[i] = vgbase + (size_t)srow * 4096 + scol;
        ldo[i] = cc * 16;
    }
    char* kldb = (char*)&Kl[half][0][0][0];
    char* vldb = (char*)&Vl[half][0][0][0];

    auto stage = [&](int t, int slot) {
        const size_t ko = (size_t)t * (64 * 6144);
        const size_t vo = (size_t)t * 128;
        const int sb = slot * 8192;
#pragma unroll
        for (int i = 0; i < 2; i++) {
            __builtin_amdgcn_global_load_lds(AS1U(kgp[i] + ko), AS3U(kldb + sb + ldo[i]), 16, 0, 0);
            __builtin_amdgcn_global_load_lds(AS1U(vgp[i] + vo), AS3U(vldb + sb + ldo[i]), 16, 0, 0);
        }
    };

    f32x16 accO[2] = {};
    f32x16 accL = {};
    const f32x16 z16 = {};
    const u32 one2 = 0x3F803F80u;
    const u32x4 onesw = {one2, one2, one2, one2};
    const bf16x8 onesf = __builtin_bit_cast(bf16x8, onesw);

    auto compute = [&](int slot) {
        const char* Kb = (const char*)&Kl[half][slot][0][0];
        const char* Vb = (const char*)&Vl[half][slot][0][0];
#pragma unroll
        for (int cc = 0; cc < 2; cc++) {
            const int tok = cc * 32 + c;
            const bf16x8 kf0 = *(const bf16x8*)(Kb + tok * 128 + ((p * 16) ^ ((tok & 7) << 4)));
            f32x16 accT = __builtin_amdgcn_mfma_f32_32x32x16_bf16(kf0, qf[0], z16, 0, 0, 0);
#pragma unroll
            for (int ch = 1; ch < 4; ch++) {
                const bf16x8 kf = *(const bf16x8*)(Kb + tok * 128 +
                                                   ((ch * 32 + p * 16) ^ ((tok & 7) << 4)));
                accT = __builtin_amdgcn_mfma_f32_32x32x16_bf16(kf, qf[ch], accT, 0, 0, 0);
            }
            float pv[16];
#pragma unroll
            for (int r = 0; r < 16; r++) pv[r] = exp2f(accT[r]);
            u32 k01 = pack2(pv[0], pv[1]),  k23 = pack2(pv[2], pv[3]);
            u32 k45 = pack2(pv[4], pv[5]),  k67 = pack2(pv[6], pv[7]);
            u32 k89 = pack2(pv[8], pv[9]),  kab = pack2(pv[10], pv[11]);
            u32 kcd = pack2(pv[12], pv[13]), kef = pack2(pv[14], pv[15]);
            asm("v_permlane32_swap_b32 %0, %1" : "+v"(k45), "+v"(k01));
            asm("v_permlane32_swap_b32 %0, %1" : "+v"(k67), "+v"(k23));
            asm("v_permlane32_swap_b32 %0, %1" : "+v"(kcd), "+v"(k89));
            asm("v_permlane32_swap_b32 %0, %1" : "+v"(kef), "+v"(kab));
            u32x4 w0w = {k01, k23, k45, k67};
            u32x4 w1w = {k89, kab, kcd, kef};
            const bf16x8 pf0 = __builtin_bit_cast(bf16x8, w0w);
            const bf16x8 pf1 = __builtin_bit_cast(bf16x8, w1w);
            accL = __builtin_amdgcn_mfma_f32_32x32x16_bf16(pf0, onesf, accL, 0, 0, 0);
            accL = __builtin_amdgcn_mfma_f32_32x32x16_bf16(pf1, onesf, accL, 0, 0, 0);
#pragma unroll
            for (int dc = 0; dc < 2; dc++) {
                const int rd = dc * 32 + c;
                const int sw = (rd & 7) << 4;
                const bf16x8 vf0 = *(const bf16x8*)(Vb + rd * 128 + ((cc * 64 + p * 16) ^ sw));
                const bf16x8 vf1 = *(const bf16x8*)(Vb + rd * 128 + ((cc * 64 + 32 + p * 16) ^ sw));
                accO[dc] = __builtin_amdgcn_mfma_f32_32x32x16_bf16(pf0, vf0, accO[dc], 0, 0, 0);
                accO[dc] = __builtin_amdgcn_mfma_f32_32x32x16_bf16(pf1, vf1, accO[dc], 0, 0, 0);
            }
        }
    };

#define KV_SYNC() do { \
        asm volatile("s_waitcnt vmcnt(0)" ::: "memory"); \
        __builtin_amdgcn_s_barrier(); \
        asm volatile("" ::: "memory"); \
    } while (0)

    stage(0, 0);
#pragma unroll 1
    for (int t = 0; t < 14; t += 2) {
        KV_SYNC(); stage(t + 1, 1); compute(0);
        KV_SYNC(); stage(t + 2, 0); compute(1);
    }
    KV_SYNC(); stage(15, 1); compute(0);
    KV_SYNC(); compute(1);
#undef KV_SYNC

    __syncthreads();
    float* ex = (float*)&Kl[0][0][0][0];
    const int xb = (qw * 64 + lane) * 49;
    if (half) {
#pragma unroll
        for (int dc = 0; dc < 2; dc++)
#pragma unroll
            for (int r = 0; r < 16; r++) ex[xb + dc * 16 + r] = accO[dc][r];
#pragma unroll
        for (int r = 0; r < 16; r++) ex[xb + 32 + r] = accL[r];
    }
    __syncthreads();
    if (!half) {
#pragma unroll
        for (int dc = 0; dc < 2; dc++)
#pragma unroll
            for (int r = 0; r < 16; r++) accO[dc][r] += ex[xb + dc * 16 + r];
#pragma unroll
        for (int r = 0; r < 16; r++) accL[r] += ex[xb + 32 + r];
        bf16* ob = Obuf + ((size_t)bh * 2048 + qbase + qw * 32) * 64;
#pragma unroll
        for (int r = 0; r < 16; r++) {
            const float inv = 1.f / accL[r];
            const int row = (r & 3) + 8 * (r >> 2) + 4 * p;
            ob[(size_t)row * 64 + c]      = (bf16)(accO[0][r] * inv);
            ob[(size_t)row * 64 + 32 + c] = (bf16)(accO[1][r] * inv);
        }
    }
}

extern "C" void kernel_launch(void* const* d_in, const int* in_sizes, int n_in,
                              void* d_out, int out_size, void* d_ws, size_t ws_size,
                              hipStream_t stream) {
    const float* q     = (const float*)d_in[0];
    const float* gamma = (const float*)d_in[3];
    const float* beta  = (const float*)d_in[4];
    const float* Wq    = (const float*)d_in[5];
    const float* bq    = (const float*)d_in[6];
    const float* Wk    = (const float*)d_in[7];
    const float* bk    = (const float*)d_in[8];
    const float* Wv    = (const float*)d_in[9];
    const float* bv    = (const float*)d_in[10];
    const float* Wo    = (const float*)d_in[11];
    const float* bo    = (const float*)d_in[12];
    float* out = (float*)d_out;

    char* ws = (char*)d_ws;
    bf16* h     = (bf16*)(ws);                          // 8 MB
    bf16* WcatT = (bf16*)(ws + (8u << 20));             // 6 MB  [3072][1024]
    bf16* WoT   = (bf16*)(ws + (14u << 20));            // 2 MB  [1024][1024]
    bf16* qkv   = (bf16*)(ws + (16u << 20));            // 24 MB [4096][3072] (Q,K used)
    bf16* Obuf  = (bf16*)(ws + (40u << 20));            // 8 MB  [B][H][T][64]
    bf16* Vtb   = (bf16*)(ws + (48u << 20));            // 8 MB  [B][H][64][T]

    prep_kernel<<<8192, 256, 0, stream>>>(q, gamma, beta, h,
                                          Wq, Wk, Wv, Wo,
                                          WcatT, WcatT + (size_t)1024 * 1024,
                                          WcatT + (size_t)2048 * 1024, WoT);

    gemm0_kernel<<<dim3(12, 16), 512, 0, stream>>>(h, WcatT, qkv, bq, bk, bv, Vtb);

    attn_kernel<<<512, 512, 0, stream>>>(qkv, Vtb, Obuf);

    gemm1_kernel<<<dim3(8, 32), 256, 0, stream>>>(Obuf, WoT, out, bo, q);
}

// Round 14
// 127.242 us; speedup vs baseline: 1.2110x; 1.2110x over previous
//
#include <hip/hip_runtime.h>

typedef __bf16 bf16;
typedef __bf16 bf16x8 __attribute__((ext_vector_type(8)));
typedef __bf16 bf16x4 __attribute__((ext_vector_type(4)));
typedef float  f32x4  __attribute__((ext_vector_type(4)));
typedef float  f32x16 __attribute__((ext_vector_type(16)));
typedef unsigned int u32;
typedef u32 u32x4 __attribute__((ext_vector_type(4)));

#define AS1U(p) ((const __attribute__((address_space(1))) unsigned int*)(p))
#define AS3U(p) ((__attribute__((address_space(3))) unsigned int*)(p))

static __device__ __forceinline__ u32 pack2(float a, float b) {
    unsigned short ua = __builtin_bit_cast(unsigned short, (bf16)a);
    unsigned short ub = __builtin_bit_cast(unsigned short, (bf16)b);
    return (u32)ua | ((u32)ub << 16);
}

// ---------------- fused: LayerNorm (blocks 0..4095) + 4x W transpose --------
__global__ void prep_kernel(const float* __restrict__ q,
                            const float* __restrict__ gamma,
                            const float* __restrict__ beta,
                            bf16* __restrict__ h,
                            const float* __restrict__ W0, const float* __restrict__ W1,
                            const float* __restrict__ W2, const float* __restrict__ W3,
                            bf16* __restrict__ D0, bf16* __restrict__ D1,
                            bf16* __restrict__ D2, bf16* __restrict__ D3) {
    __shared__ float tile[32][33];
    __shared__ float ssum[4], ssum2[4];
    const int blk = blockIdx.x;
    const int t = threadIdx.x;  // 256
    if (blk < 4096) {
        const float* xr = q + (size_t)blk * 1024;
        float4 v = ((const float4*)xr)[t];
        float s  = v.x + v.y + v.z + v.w;
        float s2 = v.x * v.x + v.y * v.y + v.z * v.z + v.w * v.w;
#pragma unroll
        for (int m = 1; m < 64; m <<= 1) {
            s  += __shfl_xor(s, m, 64);
            s2 += __shfl_xor(s2, m, 64);
        }
        const int wid = t >> 6, lane = t & 63;
        if (lane == 0) { ssum[wid] = s; ssum2[wid] = s2; }
        __syncthreads();
        s  = ssum[0] + ssum[1] + ssum[2] + ssum[3];
        s2 = ssum2[0] + ssum2[1] + ssum2[2] + ssum2[3];
        const float mu  = s * (1.f / 1024.f);
        const float var = s2 * (1.f / 1024.f) - mu * mu;
        const float rs  = rsqrtf(var + 1e-5f);
        float4 g = ((const float4*)gamma)[t];
        float4 b = ((const float4*)beta)[t];
        bf16x4 o;
        o[0] = (bf16)((v.x - mu) * rs * g.x + b.x);
        o[1] = (bf16)((v.y - mu) * rs * g.y + b.y);
        o[2] = (bf16)((v.z - mu) * rs * g.z + b.z);
        o[3] = (bf16)((v.w - mu) * rs * g.w + b.w);
        ((bf16x4*)(h + (size_t)blk * 1024))[t] = o;
    } else {
        const int z = blk - 4096;
        const float* W; bf16* D;
        switch (z >> 10) {
            case 0: W = W0; D = D0; break;
            case 1: W = W1; D = D1; break;
            case 2: W = W2; D = D2; break;
            default: W = W3; D = D3; break;
        }
        const int bi = (z & 1023) >> 5, bj = z & 31;
        const int tx = t & 31, ty = t >> 5;  // 32 x 8
#pragma unroll
        for (int i = 0; i < 4; i++) {
            tile[ty + i * 8][tx] = W[(size_t)(bi * 32 + ty + i * 8) * 1024 + bj * 32 + tx];
        }
        __syncthreads();
#pragma unroll
        for (int i = 0; i < 4; i++) {
            D[(size_t)(bj * 32 + ty + i * 8) * 1024 + bi * 32 + tx] =
                (bf16)tile[tx][ty + i * 8];
        }
    }
}

// ---------------- GEMM0: qkv = h @ WcatT^T, 128x128 tile, BK=32 -------------
// R12's proven math + 2-slot LDS ring (R7 pattern): stage(T+1) issued AFTER
// the barrier, compute(T) covers the loads' latency; ONE barrier per K-step.
// At each drain point only tile T's loads are outstanding -> vmcnt(0) == the
// counted wait. Epilogue overlays the dead ring LDS (32 KB total).
__global__ __launch_bounds__(256, 2)
void gemm0_kernel(const bf16* __restrict__ A, const bf16* __restrict__ BT,
                  bf16* __restrict__ Cb,
                  const float* __restrict__ b0, const float* __restrict__ b1,
                  const float* __restrict__ b2, bf16* __restrict__ Vt) {
    __shared__ char lds[32768];  // A ring: 2x8KB @0 ; B ring: 2x8KB @16384
    const int tid = threadIdx.x;
    const int lane = tid & 63, wave = tid >> 6;
    const int wr = wave >> 1, wc = wave & 1;
    // XCD-aware bijective block swizzle (768 % 8 == 0)
    const int bid0 = blockIdx.y * 24 + blockIdx.x;
    const int bid = (bid0 & 7) * 96 + (bid0 >> 3);
    const int tileN = (bid % 24) * 128;
    const int tileM = (bid / 24) * 128;
    const int row16 = lane & 15, g = lane >> 4;

    auto stage = [&](int T, int slot) {
        const int kt = T * 32;
        char* ab = lds + slot * 8192;
        char* bb = lds + 16384 + slot * 8192;
#pragma unroll
        for (int i = 0; i < 2; i++) {
            const int c = tid + i * 256;
            const int r = c >> 2, cbyte = (c & 3) * 16;
            const char* ga = (const char*)(A + (size_t)(tileM + r) * 1024 + kt) + cbyte;
            __builtin_amdgcn_global_load_lds(AS1U(ga), AS3U(ab + c * 16), 16, 0, 0);
            const char* gb = (const char*)(BT + (size_t)(tileN + r) * 1024 + kt) + cbyte;
            __builtin_amdgcn_global_load_lds(AS1U(gb), AS3U(bb + c * 16), 16, 0, 0);
        }
    };

    f32x4 acc[4][4] = {};
    stage(0, 0);

#pragma unroll 1
    for (int T = 0; T < 32; ++T) {
        asm volatile("s_waitcnt vmcnt(0)" ::: "memory");  // only tile T in flight
        __builtin_amdgcn_s_barrier();
        asm volatile("" ::: "memory");
        if (T < 31) stage(T + 1, (T + 1) & 1);  // flies under compute(T)
        const char* Ab = lds + (T & 1) * 8192;
        const char* Bb = lds + 16384 + (T & 1) * 8192;
        bf16x8 af[4], bfr[4];
#pragma unroll
        for (int m = 0; m < 4; m++)
            af[m] = *(const bf16x8*)(Ab + (size_t)(wr * 64 + m * 16 + row16) * 64 + g * 16);
#pragma unroll
        for (int n = 0; n < 4; n++)
            bfr[n] = *(const bf16x8*)(Bb + (size_t)(wc * 64 + n * 16 + row16) * 64 + g * 16);
        __builtin_amdgcn_s_setprio(1);
#pragma unroll
        for (int m = 0; m < 4; m++)
#pragma unroll
            for (int n = 0; n < 4; n++)
                acc[m][n] = __builtin_amdgcn_mfma_f32_16x16x32_bf16(af[m], bfr[n],
                                                                   acc[m][n], 0, 0, 0);
        __builtin_amdgcn_s_setprio(0);
    }

    // ---- epilogue via per-wave 8KB LDS region (overlaid on dead ring) ----
    __syncthreads();
    char* ep = lds + wave * 8192;  // [64][64] bf16, XOR-swizzled rows
    const bool isV = (tileN >= 2048);
    if (!isV) {
#pragma unroll
        for (int n = 0; n < 4; n++) {
            const int cl = n * 16 + row16;
            const int gc = tileN + wc * 64 + cl;
            const float bias = gc < 1024 ? b0[gc] : b1[gc - 1024];
            const float scl = gc < 1024 ? 0.18033688011112042f : 1.f;
#pragma unroll
            for (int m = 0; m < 4; m++)
#pragma unroll
                for (int j = 0; j < 4; j++) {
                    const int rl = m * 16 + g * 4 + j;
                    const float v = (acc[m][n][j] + bias) * scl;
                    *(bf16*)(ep + rl * 128 + ((cl * 2) ^ ((rl & 7) << 4))) = (bf16)v;
                }
        }
    } else {
#pragma unroll
        for (int n = 0; n < 4; n++) {
            const int dl = n * 16 + row16;
            const float bias = b2[(tileN - 2048) + wc * 64 + dl];
#pragma unroll
            for (int m = 0; m < 4; m++)
#pragma unroll
                for (int j = 0; j < 4; j++) {
                    const int tl = m * 16 + g * 4 + j;
                    const float v = fmaxf(acc[m][n][j] + bias, 0.f);
                    *(bf16*)(ep + dl * 128 + ((tl * 2) ^ ((dl & 7) << 4))) = (bf16)v;
                }
        }
    }
    asm volatile("s_waitcnt lgkmcnt(0)" ::: "memory");
    __builtin_amdgcn_sched_barrier(0);
    if (!isV) {
#pragma unroll
        for (int it = 0; it < 8; it++) {
            const int rl = (lane >> 3) + it * 8;
            const bf16x8 vrow = *(const bf16x8*)(ep + rl * 128 +
                                                 (((lane & 7) * 16) ^ ((rl & 7) << 4)));
            const int gr = tileM + wr * 64 + rl;
            const int gc = tileN + wc * 64 + (lane & 7) * 8;
            *(bf16x8*)&Cb[(size_t)gr * 3072 + gc] = vrow;
        }
    } else {
        const int bb = tileM >> 11;
        const int tbase = (tileM & 2047) + wr * 64 + (lane & 7) * 8;
#pragma unroll
        for (int it = 0; it < 8; it++) {
            const int dl = (lane >> 3) + it * 8;
            const bf16x8 vrow = *(const bf16x8*)(ep + dl * 128 +
                                                 (((lane & 7) * 16) ^ ((dl & 7) << 4)));
            const int gd = (tileN - 2048) + wc * 64 + dl;
            const int hh = gd >> 6, dd = gd & 63;
            *(bf16x8*)&Vt[(((size_t)bb * 16 + hh) * 64 + dd) * 2048 + tbase] = vrow;
        }
    }
}

// ---------------- GEMM1: out = Obuf @ WoT^T + bo + resid (fp32) -------------
// 128x128 tile, BK=32, 4 waves; LDS-coalesced float4 epilogue. (R12 proven)
__global__ void gemm1_kernel(const bf16* __restrict__ A, const bf16* __restrict__ BT,
                             float* __restrict__ Cf, const float* __restrict__ bo,
                             const float* __restrict__ resid) {
    __shared__ bf16 Asm[128][32];
    __shared__ bf16 Bsm[128][32];
    const int tid = threadIdx.x;
    const int lane = tid & 63, wave = tid >> 6;
    const int wr = wave >> 1, wc = wave & 1;
    const int nwg = gridDim.x * gridDim.y;
    const int bid0 = blockIdx.y * gridDim.x + blockIdx.x;
    const int bid = (bid0 & 7) * (nwg >> 3) + (bid0 >> 3);
    const int tileN = (bid % gridDim.x) * 128;
    const int tileM = (bid / gridDim.x) * 128;
    const int row16 = lane & 15, g = lane >> 4;

    f32x4 acc[4][4] = {};

    for (int kt = 0; kt < 1024; kt += 32) {
#pragma unroll
        for (int i = 0; i < 2; i++) {
            int c = tid + i * 256;
            int r = c >> 2, cb = (c & 3) * 16;
            const char* g_ = (const char*)(A + (size_t)(tileM + r) * 1024 + kt) + cb;
            __builtin_amdgcn_global_load_lds(AS1U(g_), AS3U((char*)&Asm[0][0] + c * 16), 16, 0, 0);
        }
#pragma unroll
        for (int i = 0; i < 2; i++) {
            int c = tid + i * 256;
            int r = c >> 2, cb = (c & 3) * 16;
            const char* g_ = (const char*)(BT + (size_t)(tileN + r) * 1024 + kt) + cb;
            __builtin_amdgcn_global_load_lds(AS1U(g_), AS3U((char*)&Bsm[0][0] + c * 16), 16, 0, 0);
        }
        __syncthreads();
        bf16x8 af[4], bfr[4];
#pragma unroll
        for (int m = 0; m < 4; m++)
            af[m] = *(const bf16x8*)&Asm[wr * 64 + m * 16 + row16][g * 8];
#pragma unroll
        for (int n = 0; n < 4; n++)
            bfr[n] = *(const bf16x8*)&Bsm[wc * 64 + n * 16 + row16][g * 8];
#pragma unroll
        for (int m = 0; m < 4; m++)
#pragma unroll
            for (int n = 0; n < 4; n++)
                acc[m][n] = __builtin_amdgcn_mfma_f32_16x16x32_bf16(af[m], bfr[n],
                                                                   acc[m][n], 0, 0, 0);
        __syncthreads();
    }
    __shared__ float Epf[4][64][66];
    float* ep = &Epf[wave][0][0];
#pragma unroll
    for (int n = 0; n < 4; n++) {
        const int cl = n * 16 + row16;
        const float bias = bo[tileN + wc * 64 + cl];
#pragma unroll
        for (int m = 0; m < 4; m++)
#pragma unroll
            for (int j = 0; j < 4; j++) {
                const int rl = m * 16 + g * 4 + j;
                ep[rl * 66 + cl] = acc[m][n][j] + bias;
            }
    }
    asm volatile("s_waitcnt lgkmcnt(0)" ::: "memory");
    __builtin_amdgcn_sched_barrier(0);
    const int rl0 = lane >> 4;
    const int cl0 = (lane & 15) * 4;
#pragma unroll
    for (int it = 0; it < 16; it++) {
        const int rl = rl0 + it * 4;
        float4 v = *(const float4*)&ep[rl * 66 + cl0];
        const int gr = tileM + wr * 64 + rl;
        const int gc = tileN + wc * 64 + cl0;
        const float4 rv = *(const float4*)&resid[(size_t)gr * 1024 + gc];
        v.x += rv.x; v.y += rv.y; v.z += rv.z; v.w += rv.w;
        *(float4*)&Cf[(size_t)gr * 1024 + gc] = v;
    }
}

// ---------------- flash attention, 32x32 MFMA, in-block KV split ------------
// (unchanged from R12: 512 blocks x 8 waves, ones-MFMA denominator)
__global__ __launch_bounds__(512, 4)
void attn_kernel(const bf16* __restrict__ qkv, const bf16* __restrict__ Vt,
                 bf16* __restrict__ Obuf) {
    const int bid = blockIdx.x;
    const int swz = (bid & 7) * 64 + (bid >> 3);
    const int bh = swz >> 4, qt = swz & 15;
    const int b = bh >> 4, h = bh & 15;
    const int qbase = qt * 128;
    const int tid = threadIdx.x;
    const int lane = tid & 63, wv = tid >> 6;
    const int half = wv >> 2, qw = wv & 3;
    const int c = lane & 31, p = lane >> 5;

    __shared__ bf16 Kl[2][2][64][64];
    __shared__ bf16 Vl[2][2][64][64];

    const bf16* qrow = qkv + (size_t)(b * 2048 + qbase + qw * 32 + c) * 3072 + h * 64;
    bf16x8 qf[4];
#pragma unroll
    for (int ch = 0; ch < 4; ch++)
        qf[ch] = *(const bf16x8*)(qrow + ch * 16 + p * 8);

    const char* kgbase = (const char*)(qkv + (size_t)b * 2048 * 3072 + 1024 + h * 64)
                         + (size_t)(half * 1024) * 6144;
    const char* vgbase = (const char*)(Vt + (size_t)bh * 64 * 2048) + half * 2048;
    const int ht = tid & 255;
    const char* kgp[2]; const char* vgp[2]; int ldo[2];
#pragma unroll
    for (int i = 0; i < 2; i++) {
        const int cc = ht + i * 256;
        const int srow = cc >> 3;
        const int scol = ((cc & 7) * 16) ^ ((srow & 7) << 4);
        kgp[i] = kgbase + (size_t)srow * 6144 + scol;
        vgp[i] = vgbase + (size_t)srow * 4096 + scol;
        ldo[i] = cc * 16;
    }
    char* kldb = (char*)&Kl[half][0][0][0];
    char* vldb = (char*)&Vl[half][0][0][0];

    auto stage = [&](int t, int slot) {
        const size_t ko = (size_t)t * (64 * 6144);
        const size_t vo = (size_t)t * 128;
        const int sb = slot * 8192;
#pragma unroll
        for (int i = 0; i < 2; i++) {
            __builtin_amdgcn_global_load_lds(AS1U(kgp[i] + ko), AS3U(kldb + sb + ldo[i]), 16, 0, 0);
            __builtin_amdgcn_global_load_lds(AS1U(vgp[i] + vo), AS3U(vldb + sb + ldo[i]), 16, 0, 0);
        }
    };

    f32x16 accO[2] = {};
    f32x16 accL = {};
    const f32x16 z16 = {};
    const u32 one2 = 0x3F803F80u;
    const u32x4 onesw = {one2, one2, one2, one2};
    const bf16x8 onesf = __builtin_bit_cast(bf16x8, onesw);

    auto compute = [&](int slot) {
        const char* Kb = (const char*)&Kl[half][slot][0][0];
        const char* Vb = (const char*)&Vl[half][slot][0][0];
#pragma unroll
        for (int cc = 0; cc < 2; cc++) {
            const int tok = cc * 32 + c;
            const bf16x8 kf0 = *(const bf16x8*)(Kb + tok * 128 + ((p * 16) ^ ((tok & 7) << 4)));
            f32x16 accT = __builtin_amdgcn_mfma_f32_32x32x16_bf16(kf0, qf[0], z16, 0, 0, 0);
#pragma unroll
            for (int ch = 1; ch < 4; ch++) {
                const bf16x8 kf = *(const bf16x8*)(Kb + tok * 128 +
                                                   ((ch * 32 + p * 16) ^ ((tok & 7) << 4)));
                accT = __builtin_amdgcn_mfma_f32_32x32x16_bf16(kf, qf[ch], accT, 0, 0, 0);
            }
            float pv[16];
#pragma unroll
            for (int r = 0; r < 16; r++) pv[r] = exp2f(accT[r]);
            u32 k01 = pack2(pv[0], pv[1]),  k23 = pack2(pv[2], pv[3]);
            u32 k45 = pack2(pv[4], pv[5]),  k67 = pack2(pv[6], pv[7]);
            u32 k89 = pack2(pv[8], pv[9]),  kab = pack2(pv[10], pv[11]);
            u32 kcd = pack2(pv[12], pv[13]), kef = pack2(pv[14], pv[15]);
            asm("v_permlane32_swap_b32 %0, %1" : "+v"(k45), "+v"(k01));
            asm("v_permlane32_swap_b32 %0, %1" : "+v"(k67), "+v"(k23));
            asm("v_permlane32_swap_b32 %0, %1" : "+v"(kcd), "+v"(k89));
            asm("v_permlane32_swap_b32 %0, %1" : "+v"(kef), "+v"(kab));
            u32x4 w0w = {k01, k23, k45, k67};
            u32x4 w1w = {k89, kab, kcd, kef};
            const bf16x8 pf0 = __builtin_bit_cast(bf16x8, w0w);
            const bf16x8 pf1 = __builtin_bit_cast(bf16x8, w1w);
            accL = __builtin_amdgcn_mfma_f32_32x32x16_bf16(pf0, onesf, accL, 0, 0, 0);
            accL = __builtin_amdgcn_mfma_f32_32x32x16_bf16(pf1, onesf, accL, 0, 0, 0);
#pragma unroll
            for (int dc = 0; dc < 2; dc++) {
                const int rd = dc * 32 + c;
                const int sw = (rd & 7) << 4;
                const bf16x8 vf0 = *(const bf16x8*)(Vb + rd * 128 + ((cc * 64 + p * 16) ^ sw));
                const bf16x8 vf1 = *(const bf16x8*)(Vb + rd * 128 + ((cc * 64 + 32 + p * 16) ^ sw));
                accO[dc] = __builtin_amdgcn_mfma_f32_32x32x16_bf16(pf0, vf0, accO[dc], 0, 0, 0);
                accO[dc] = __builtin_amdgcn_mfma_f32_32x32x16_bf16(pf1, vf1, accO[dc], 0, 0, 0);
            }
        }
    };

#define KV_SYNC() do { \
        asm volatile("s_waitcnt vmcnt(0)" ::: "memory"); \
        __builtin_amdgcn_s_barrier(); \
        asm volatile("" ::: "memory"); \
    } while (0)

    stage(0, 0);
#pragma unroll 1
    for (int t = 0; t < 14; t += 2) {
        KV_SYNC(); stage(t + 1, 1); compute(0);
        KV_SYNC(); stage(t + 2, 0); compute(1);
    }
    KV_SYNC(); stage(15, 1); compute(0);
    KV_SYNC(); compute(1);
#undef KV_SYNC

    __syncthreads();
    float* ex = (float*)&Kl[0][0][0][0];
    const int xb = (qw * 64 + lane) * 49;
    if (half) {
#pragma unroll
        for (int dc = 0; dc < 2; dc++)
#pragma unroll
            for (int r = 0; r < 16; r++) ex[xb + dc * 16 + r] = accO[dc][r];
#pragma unroll
        for (int r = 0; r < 16; r++) ex[xb + 32 + r] = accL[r];
    }
    __syncthreads();
    if (!half) {
#pragma unroll
        for (int dc = 0; dc < 2; dc++)
#pragma unroll
            for (int r = 0; r < 16; r++) accO[dc][r] += ex[xb + dc * 16 + r];
#pragma unroll
        for (int r = 0; r < 16; r++) accL[r] += ex[xb + 32 + r];
        bf16* ob = Obuf + ((size_t)bh * 2048 + qbase + qw * 32) * 64;
#pragma unroll
        for (int r = 0; r < 16; r++) {
            const float inv = 1.f / accL[r];
            const int row = (r & 3) + 8 * (r >> 2) + 4 * p;
            ob[(size_t)row * 64 + c]      = (bf16)(accO[0][r] * inv);
            ob[(size_t)row * 64 + 32 + c] = (bf16)(accO[1][r] * inv);
        }
    }
}

extern "C" void kernel_launch(void* const* d_in, const int* in_sizes, int n_in,
                              void* d_out, int out_size, void* d_ws, size_t ws_size,
                              hipStream_t stream) {
    const float* q     = (const float*)d_in[0];
    const float* gamma = (const float*)d_in[3];
    const float* beta  = (const float*)d_in[4];
    const float* Wq    = (const float*)d_in[5];
    const float* bq    = (const float*)d_in[6];
    const float* Wk    = (const float*)d_in[7];
    const float* bk    = (const float*)d_in[8];
    const float* Wv    = (const float*)d_in[9];
    const float* bv    = (const float*)d_in[10];
    const float* Wo    = (const float*)d_in[11];
    const float* bo    = (const float*)d_in[12];
    float* out = (float*)d_out;

    char* ws = (char*)d_ws;
    bf16* h     = (bf16*)(ws);                          // 8 MB
    bf16* WcatT = (bf16*)(ws + (8u << 20));             // 6 MB  [3072][1024]
    bf16* WoT   = (bf16*)(ws + (14u << 20));            // 2 MB  [1024][1024]
    bf16* qkv   = (bf16*)(ws + (16u << 20));            // 24 MB [4096][3072] (Q,K used)
    bf16* Obuf  = (bf16*)(ws + (40u << 20));            // 8 MB  [B][H][T][64]
    bf16* Vtb   = (bf16*)(ws + (48u << 20));            // 8 MB  [B][H][64][T]

    prep_kernel<<<8192, 256, 0, stream>>>(q, gamma, beta, h,
                                          Wq, Wk, Wv, Wo,
                                          WcatT, WcatT + (size_t)1024 * 1024,
                                          WcatT + (size_t)2048 * 1024, WoT);

    gemm0_kernel<<<dim3(24, 32), 256, 0, stream>>>(h, WcatT, qkv, bq, bk, bv, Vtb);

    attn_kernel<<<512, 512, 0, stream>>>(qkv, Vtb, Obuf);

    gemm1_kernel<<<dim3(8, 32), 256, 0, stream>>>(Obuf, WoT, out, bo, q);
}

// Round 15
// 125.121 us; speedup vs baseline: 1.2316x; 1.0169x over previous
//
#include <hip/hip_runtime.h>

typedef __bf16 bf16;
typedef __bf16 bf16x8 __attribute__((ext_vector_type(8)));
typedef __bf16 bf16x4 __attribute__((ext_vector_type(4)));
typedef float  f32x4  __attribute__((ext_vector_type(4)));
typedef float  f32x16 __attribute__((ext_vector_type(16)));
typedef unsigned int u32;
typedef u32 u32x4 __attribute__((ext_vector_type(4)));

#define AS1U(p) ((const __attribute__((address_space(1))) unsigned int*)(p))
#define AS3U(p) ((__attribute__((address_space(3))) unsigned int*)(p))

static __device__ __forceinline__ u32 pack2(float a, float b) {
    unsigned short ua = __builtin_bit_cast(unsigned short, (bf16)a);
    unsigned short ub = __builtin_bit_cast(unsigned short, (bf16)b);
    return (u32)ua | ((u32)ub << 16);
}

// ---------------- fused: LayerNorm (blocks 0..4095) + 4x W transpose --------
__global__ void prep_kernel(const float* __restrict__ q,
                            const float* __restrict__ gamma,
                            const float* __restrict__ beta,
                            bf16* __restrict__ h,
                            const float* __restrict__ W0, const float* __restrict__ W1,
                            const float* __restrict__ W2, const float* __restrict__ W3,
                            bf16* __restrict__ D0, bf16* __restrict__ D1,
                            bf16* __restrict__ D2, bf16* __restrict__ D3) {
    __shared__ float tile[32][33];
    __shared__ float ssum[4], ssum2[4];
    const int blk = blockIdx.x;
    const int t = threadIdx.x;  // 256
    if (blk < 4096) {
        const float* xr = q + (size_t)blk * 1024;
        float4 v = ((const float4*)xr)[t];
        float s  = v.x + v.y + v.z + v.w;
        float s2 = v.x * v.x + v.y * v.y + v.z * v.z + v.w * v.w;
#pragma unroll
        for (int m = 1; m < 64; m <<= 1) {
            s  += __shfl_xor(s, m, 64);
            s2 += __shfl_xor(s2, m, 64);
        }
        const int wid = t >> 6, lane = t & 63;
        if (lane == 0) { ssum[wid] = s; ssum2[wid] = s2; }
        __syncthreads();
        s  = ssum[0] + ssum[1] + ssum[2] + ssum[3];
        s2 = ssum2[0] + ssum2[1] + ssum2[2] + ssum2[3];
        const float mu  = s * (1.f / 1024.f);
        const float var = s2 * (1.f / 1024.f) - mu * mu;
        const float rs  = rsqrtf(var + 1e-5f);
        float4 g = ((const float4*)gamma)[t];
        float4 b = ((const float4*)beta)[t];
        bf16x4 o;
        o[0] = (bf16)((v.x - mu) * rs * g.x + b.x);
        o[1] = (bf16)((v.y - mu) * rs * g.y + b.y);
        o[2] = (bf16)((v.z - mu) * rs * g.z + b.z);
        o[3] = (bf16)((v.w - mu) * rs * g.w + b.w);
        ((bf16x4*)(h + (size_t)blk * 1024))[t] = o;
    } else {
        const int z = blk - 4096;
        const float* W; bf16* D;
        switch (z >> 10) {
            case 0: W = W0; D = D0; break;
            case 1: W = W1; D = D1; break;
            case 2: W = W2; D = D2; break;
            default: W = W3; D = D3; break;
        }
        const int bi = (z & 1023) >> 5, bj = z & 31;
        const int tx = t & 31, ty = t >> 5;  // 32 x 8
#pragma unroll
        for (int i = 0; i < 4; i++) {
            tile[ty + i * 8][tx] = W[(size_t)(bi * 32 + ty + i * 8) * 1024 + bj * 32 + tx];
        }
        __syncthreads();
#pragma unroll
        for (int i = 0; i < 4; i++) {
            D[(size_t)(bj * 32 + ty + i * 8) * 1024 + bi * 32 + tx] =
                (bf16)tile[tx][ty + i * 8];
        }
    }
}

// ---------------- GEMM0: qkv = h @ WcatT^T, 128x128 tile, BK=32 -------------
// 3-slot LDS ring, prefetch depth 2, COUNTED vmcnt(4): tile T+1's loads stay
// in flight across the barrier; each tile gets ~2 compute phases of latency
// cover. 48KB LDS -> 3 blocks/CU (matches 768-block grid exactly).
__global__ __launch_bounds__(256, 2)
void gemm0_kernel(const bf16* __restrict__ A, const bf16* __restrict__ BT,
                  bf16* __restrict__ Cb,
                  const float* __restrict__ b0, const float* __restrict__ b1,
                  const float* __restrict__ b2, bf16* __restrict__ Vt) {
    __shared__ char lds[49152];  // A slots: 3x8KB @0 ; B slots: 3x8KB @24576
    const int tid = threadIdx.x;
    const int lane = tid & 63, wave = tid >> 6;
    const int wr = wave >> 1, wc = wave & 1;
    // XCD-aware bijective block swizzle (768 % 8 == 0)
    const int bid0 = blockIdx.y * 24 + blockIdx.x;
    const int bid = (bid0 & 7) * 96 + (bid0 >> 3);
    const int tileN = (bid % 24) * 128;
    const int tileM = (bid / 24) * 128;
    const int row16 = lane & 15, g = lane >> 4;

    auto stage = [&](int T, int slot) {
        const int kt = T * 32;
        char* ab = lds + slot * 8192;
        char* bb = lds + 24576 + slot * 8192;
#pragma unroll
        for (int i = 0; i < 2; i++) {
            const int c = tid + i * 256;
            const int r = c >> 2, cbyte = (c & 3) * 16;
            const char* ga = (const char*)(A + (size_t)(tileM + r) * 1024 + kt) + cbyte;
            __builtin_amdgcn_global_load_lds(AS1U(ga), AS3U(ab + c * 16), 16, 0, 0);
            const char* gb = (const char*)(BT + (size_t)(tileN + r) * 1024 + kt) + cbyte;
            __builtin_amdgcn_global_load_lds(AS1U(gb), AS3U(bb + c * 16), 16, 0, 0);
        }
    };

    f32x4 acc[4][4] = {};
    stage(0, 0);
    stage(1, 1);

#pragma unroll 1
    for (int T = 0; T < 32; ++T) {
        // counted wait: tile T done; tile T+1's 4 loads/thread stay in flight
        if (T < 31) { asm volatile("s_waitcnt vmcnt(4)" ::: "memory"); }
        else        { asm volatile("s_waitcnt vmcnt(0)" ::: "memory"); }
        __builtin_amdgcn_s_barrier();
        asm volatile("" ::: "memory");
        if (T < 30) stage(T + 2, (T + 2) % 3);  // slot freed at T-1 (barrier-ordered)
        const int sl = T % 3;
        const char* Ab = lds + sl * 8192;
        const char* Bb = lds + 24576 + sl * 8192;
        bf16x8 af[4], bfr[4];
#pragma unroll
        for (int m = 0; m < 4; m++)
            af[m] = *(const bf16x8*)(Ab + (size_t)(wr * 64 + m * 16 + row16) * 64 + g * 16);
#pragma unroll
        for (int n = 0; n < 4; n++)
            bfr[n] = *(const bf16x8*)(Bb + (size_t)(wc * 64 + n * 16 + row16) * 64 + g * 16);
        __builtin_amdgcn_s_setprio(1);
#pragma unroll
        for (int m = 0; m < 4; m++)
#pragma unroll
            for (int n = 0; n < 4; n++)
                acc[m][n] = __builtin_amdgcn_mfma_f32_16x16x32_bf16(af[m], bfr[n],
                                                                   acc[m][n], 0, 0, 0);
        __builtin_amdgcn_s_setprio(0);
    }

    // ---- epilogue via per-wave 8KB LDS region (overlaid on dead ring) ----
    __syncthreads();
    char* ep = lds + wave * 8192;  // [64][64] bf16, XOR-swizzled rows
    const bool isV = (tileN >= 2048);
    if (!isV) {
#pragma unroll
        for (int n = 0; n < 4; n++) {
            const int cl = n * 16 + row16;
            const int gc = tileN + wc * 64 + cl;
            const float bias = gc < 1024 ? b0[gc] : b1[gc - 1024];
            const float scl = gc < 1024 ? 0.18033688011112042f : 1.f;
#pragma unroll
            for (int m = 0; m < 4; m++)
#pragma unroll
                for (int j = 0; j < 4; j++) {
                    const int rl = m * 16 + g * 4 + j;
                    const float v = (acc[m][n][j] + bias) * scl;
                    *(bf16*)(ep + rl * 128 + ((cl * 2) ^ ((rl & 7) << 4))) = (bf16)v;
                }
        }
    } else {
#pragma unroll
        for (int n = 0; n < 4; n++) {
            const int dl = n * 16 + row16;
            const float bias = b2[(tileN - 2048) + wc * 64 + dl];
#pragma unroll
            for (int m = 0; m < 4; m++)
#pragma unroll
                for (int j = 0; j < 4; j++) {
                    const int tl = m * 16 + g * 4 + j;
                    const float v = fmaxf(acc[m][n][j] + bias, 0.f);
                    *(bf16*)(ep + dl * 128 + ((tl * 2) ^ ((dl & 7) << 4))) = (bf16)v;
                }
        }
    }
    asm volatile("s_waitcnt lgkmcnt(0)" ::: "memory");
    __builtin_amdgcn_sched_barrier(0);
    if (!isV) {
#pragma unroll
        for (int it = 0; it < 8; it++) {
            const int rl = (lane >> 3) + it * 8;
            const bf16x8 vrow = *(const bf16x8*)(ep + rl * 128 +
                                                 (((lane & 7) * 16) ^ ((rl & 7) << 4)));
            const int gr = tileM + wr * 64 + rl;
            const int gc = tileN + wc * 64 + (lane & 7) * 8;
            *(bf16x8*)&Cb[(size_t)gr * 3072 + gc] = vrow;
        }
    } else {
        const int bb = tileM >> 11;
        const int tbase = (tileM & 2047) + wr * 64 + (lane & 7) * 8;
#pragma unroll
        for (int it = 0; it < 8; it++) {
            const int dl = (lane >> 3) + it * 8;
            const bf16x8 vrow = *(const bf16x8*)(ep + dl * 128 +
                                                 (((lane & 7) * 16) ^ ((dl & 7) << 4)));
            const int gd = (tileN - 2048) + wc * 64 + dl;
            const int hh = gd >> 6, dd = gd & 63;
            *(bf16x8*)&Vt[(((size_t)bb * 16 + hh) * 64 + dd) * 2048 + tbase] = vrow;
        }
    }
}

// ---------------- GEMM1: out = Obuf @ WoT^T + bo + resid (fp32) -------------
// 3-slot ring + counted vmcnt(4) (1 block/CU -> no multi-block cover, so the
// ring is the only latency hiding). Epilogue overlays the ring buffer.
__global__ __launch_bounds__(256, 2)
void gemm1_kernel(const bf16* __restrict__ A, const bf16* __restrict__ BT,
                  float* __restrict__ Cf, const float* __restrict__ bo,
                  const float* __restrict__ resid) {
    __shared__ char lds[67584];  // ring: A 3x8KB @0, B 3x8KB @24576; epi: fp32 [4][64][66]
    const int tid = threadIdx.x;
    const int lane = tid & 63, wave = tid >> 6;
    const int wr = wave >> 1, wc = wave & 1;
    const int nwg = gridDim.x * gridDim.y;
    const int bid0 = blockIdx.y * gridDim.x + blockIdx.x;
    const int bid = (bid0 & 7) * (nwg >> 3) + (bid0 >> 3);
    const int tileN = (bid % gridDim.x) * 128;
    const int tileM = (bid / gridDim.x) * 128;
    const int row16 = lane & 15, g = lane >> 4;

    auto stage = [&](int T, int slot) {
        const int kt = T * 32;
        char* ab = lds + slot * 8192;
        char* bb = lds + 24576 + slot * 8192;
#pragma unroll
        for (int i = 0; i < 2; i++) {
            const int c = tid + i * 256;
            const int r = c >> 2, cbyte = (c & 3) * 16;
            const char* ga = (const char*)(A + (size_t)(tileM + r) * 1024 + kt) + cbyte;
            __builtin_amdgcn_global_load_lds(AS1U(ga), AS3U(ab + c * 16), 16, 0, 0);
            const char* gb = (const char*)(BT + (size_t)(tileN + r) * 1024 + kt) + cbyte;
            __builtin_amdgcn_global_load_lds(AS1U(gb), AS3U(bb + c * 16), 16, 0, 0);
        }
    };

    f32x4 acc[4][4] = {};
    stage(0, 0);
    stage(1, 1);

#pragma unroll 1
    for (int T = 0; T < 32; ++T) {
        if (T < 31) { asm volatile("s_waitcnt vmcnt(4)" ::: "memory"); }
        else        { asm volatile("s_waitcnt vmcnt(0)" ::: "memory"); }
        __builtin_amdgcn_s_barrier();
        asm volatile("" ::: "memory");
        if (T < 30) stage(T + 2, (T + 2) % 3);
        const int sl = T % 3;
        const char* Ab = lds + sl * 8192;
        const char* Bb = lds + 24576 + sl * 8192;
        bf16x8 af[4], bfr[4];
#pragma unroll
        for (int m = 0; m < 4; m++)
            af[m] = *(const bf16x8*)(Ab + (size_t)(wr * 64 + m * 16 + row16) * 64 + g * 16);
#pragma unroll
        for (int n = 0; n < 4; n++)
            bfr[n] = *(const bf16x8*)(Bb + (size_t)(wc * 64 + n * 16 + row16) * 64 + g * 16);
        __builtin_amdgcn_s_setprio(1);
#pragma unroll
        for (int m = 0; m < 4; m++)
#pragma unroll
            for (int n = 0; n < 4; n++)
                acc[m][n] = __builtin_amdgcn_mfma_f32_16x16x32_bf16(af[m], bfr[n],
                                                                   acc[m][n], 0, 0, 0);
        __builtin_amdgcn_s_setprio(0);
    }

    // ---- epilogue: fp32 LDS coalescing (overlaid on dead ring) ----
    __syncthreads();
    float* ep = (float*)lds + (size_t)wave * 64 * 66;
#pragma unroll
    for (int n = 0; n < 4; n++) {
        const int cl = n * 16 + row16;
        const float bias = bo[tileN + wc * 64 + cl];
#pragma unroll
        for (int m = 0; m < 4; m++)
#pragma unroll
            for (int j = 0; j < 4; j++) {
                const int rl = m * 16 + g * 4 + j;
                ep[rl * 66 + cl] = acc[m][n][j] + bias;
            }
    }
    asm volatile("s_waitcnt lgkmcnt(0)" ::: "memory");
    __builtin_amdgcn_sched_barrier(0);
    const int rl0 = lane >> 4;
    const int cl0 = (lane & 15) * 4;
#pragma unroll
    for (int it = 0; it < 16; it++) {
        const int rl = rl0 + it * 4;
        float4 v = *(const float4*)&ep[rl * 66 + cl0];
        const int gr = tileM + wr * 64 + rl;
        const int gc = tileN + wc * 64 + cl0;
        const float4 rv = *(const float4*)&resid[(size_t)gr * 1024 + gc];
        v.x += rv.x; v.y += rv.y; v.z += rv.z; v.w += rv.w;
        *(float4*)&Cf[(size_t)gr * 1024 + gc] = v;
    }
}

// ---------------- flash attention, 32x32 MFMA, in-block KV split ------------
// (unchanged from R12: 512 blocks x 8 waves, ones-MFMA denominator)
__global__ __launch_bounds__(512, 4)
void attn_kernel(const bf16* __restrict__ qkv, const bf16* __restrict__ Vt,
                 bf16* __restrict__ Obuf) {
    const int bid = blockIdx.x;
    const int swz = (bid & 7) * 64 + (bid >> 3);
    const int bh = swz >> 4, qt = swz & 15;
    const int b = bh >> 4, h = bh & 15;
    const int qbase = qt * 128;
    const int tid = threadIdx.x;
    const int lane = tid & 63, wv = tid >> 6;
    const int half = wv >> 2, qw = wv & 3;
    const int c = lane & 31, p = lane >> 5;

    __shared__ bf16 Kl[2][2][64][64];
    __shared__ bf16 Vl[2][2][64][64];

    const bf16* qrow = qkv + (size_t)(b * 2048 + qbase + qw * 32 + c) * 3072 + h * 64;
    bf16x8 qf[4];
#pragma unroll
    for (int ch = 0; ch < 4; ch++)
        qf[ch] = *(const bf16x8*)(qrow + ch * 16 + p * 8);

    const char* kgbase = (const char*)(qkv + (size_t)b * 2048 * 3072 + 1024 + h * 64)
                         + (size_t)(half * 1024) * 6144;
    const char* vgbase = (const char*)(Vt + (size_t)bh * 64 * 2048) + half * 2048;
    const int ht = tid & 255;
    const char* kgp[2]; const char* vgp[2]; int ldo[2];
#pragma unroll
    for (int i = 0; i < 2; i++) {
        const int cc = ht + i * 256;
        const int srow = cc >> 3;
        const int scol = ((cc & 7) * 16) ^ ((srow & 7) << 4);
        kgp[i] = kgbase + (size_t)srow * 6144 + scol;
        vgp[i] = vgbase + (size_t)srow * 4096 + scol;
        ldo[i] = cc * 16;
    }
    char* kldb = (char*)&Kl[half][0][0][0];
    char* vldb = (char*)&Vl[half][0][0][0];

    auto stage = [&](int t, int slot) {
        const size_t ko = (size_t)t * (64 * 6144);
        const size_t vo = (size_t)t * 128;
        const int sb = slot * 8192;
#pragma unroll
        for (int i = 0; i < 2; i++) {
            __builtin_amdgcn_global_load_lds(AS1U(kgp[i] + ko), AS3U(kldb + sb + ldo[i]), 16, 0, 0);
            __builtin_amdgcn_global_load_lds(AS1U(vgp[i] + vo), AS3U(vldb + sb + ldo[i]), 16, 0, 0);
        }
    };

    f32x16 accO[2] = {};
    f32x16 accL = {};
    const f32x16 z16 = {};
    const u32 one2 = 0x3F803F80u;
    const u32x4 onesw = {one2, one2, one2, one2};
    const bf16x8 onesf = __builtin_bit_cast(bf16x8, onesw);

    auto compute = [&](int slot) {
        const char* Kb = (const char*)&Kl[half][slot][0][0];
        const char* Vb = (const char*)&Vl[half][slot][0][0];
#pragma unroll
        for (int cc = 0; cc < 2; cc++) {
            const int tok = cc * 32 + c;
            const bf16x8 kf0 = *(const bf16x8*)(Kb + tok * 128 + ((p * 16) ^ ((tok & 7) << 4)));
            f32x16 accT = __builtin_amdgcn_mfma_f32_32x32x16_bf16(kf0, qf[0], z16, 0, 0, 0);
#pragma unroll
            for (int ch = 1; ch < 4; ch++) {
                const bf16x8 kf = *(const bf16x8*)(Kb + tok * 128 +
                                                   ((ch * 32 + p * 16) ^ ((tok & 7) << 4)));
                accT = __builtin_amdgcn_mfma_f32_32x32x16_bf16(kf, qf[ch], accT, 0, 0, 0);
            }
            float pv[16];
#pragma unroll
            for (int r = 0; r < 16; r++) pv[r] = exp2f(accT[r]);
            u32 k01 = pack2(pv[0], pv[1]),  k23 = pack2(pv[2], pv[3]);
            u32 k45 = pack2(pv[4], pv[5]),  k67 = pack2(pv[6], pv[7]);
            u32 k89 = pack2(pv[8], pv[9]),  kab = pack2(pv[10], pv[11]);
            u32 kcd = pack2(pv[12], pv[13]), kef = pack2(pv[14], pv[15]);
            asm("v_permlane32_swap_b32 %0, %1" : "+v"(k45), "+v"(k01));
            asm("v_permlane32_swap_b32 %0, %1" : "+v"(k67), "+v"(k23));
            asm("v_permlane32_swap_b32 %0, %1" : "+v"(kcd), "+v"(k89));
            asm("v_permlane32_swap_b32 %0, %1" : "+v"(kef), "+v"(kab));
            u32x4 w0w = {k01, k23, k45, k67};
            u32x4 w1w = {k89, kab, kcd, kef};
            const bf16x8 pf0 = __builtin_bit_cast(bf16x8, w0w);
            const bf16x8 pf1 = __builtin_bit_cast(bf16x8, w1w);
            accL = __builtin_amdgcn_mfma_f32_32x32x16_bf16(pf0, onesf, accL, 0, 0, 0);
            accL = __builtin_amdgcn_mfma_f32_32x32x16_bf16(pf1, onesf, accL, 0, 0, 0);
#pragma unroll
            for (int dc = 0; dc < 2; dc++) {
                const int rd = dc * 32 + c;
                const int sw = (rd & 7) << 4;
                const bf16x8 vf0 = *(const bf16x8*)(Vb + rd * 128 + ((cc * 64 + p * 16) ^ sw));
                const bf16x8 vf1 = *(const bf16x8*)(Vb + rd * 128 + ((cc * 64 + 32 + p * 16) ^ sw));
                accO[dc] = __builtin_amdgcn_mfma_f32_32x32x16_bf16(pf0, vf0, accO[dc], 0, 0, 0);
                accO[dc] = __builtin_amdgcn_mfma_f32_32x32x16_bf16(pf1, vf1, accO[dc], 0, 0, 0);
            }
        }
    };

#define KV_SYNC() do { \
        asm volatile("s_waitcnt vmcnt(0)" ::: "memory"); \
        __builtin_amdgcn_s_barrier(); \
        asm volatile("" ::: "memory"); \
    } while (0)

    stage(0, 0);
#pragma unroll 1
    for (int t = 0; t < 14; t += 2) {
        KV_SYNC(); stage(t + 1, 1); compute(0);
        KV_SYNC(); stage(t + 2, 0); compute(1);
    }
    KV_SYNC(); stage(15, 1); compute(0);
    KV_SYNC(); compute(1);
#undef KV_SYNC

    __syncthreads();
    float* ex = (float*)&Kl[0][0][0][0];
    const int xb = (qw * 64 + lane) * 49;
    if (half) {
#pragma unroll
        for (int dc = 0; dc < 2; dc++)
#pragma unroll
            for (int r = 0; r < 16; r++) ex[xb + dc * 16 + r] = accO[dc][r];
#pragma unroll
        for (int r = 0; r < 16; r++) ex[xb + 32 + r] = accL[r];
    }
    __syncthreads();
    if (!half) {
#pragma unroll
        for (int dc = 0; dc < 2; dc++)
#pragma unroll
            for (int r = 0; r < 16; r++) accO[dc][r] += ex[xb + dc * 16 + r];
#pragma unroll
        for (int r = 0; r < 16; r++) accL[r] += ex[xb + 32 + r];
        bf16* ob = Obuf + ((size_t)bh * 2048 + qbase + qw * 32) * 64;
#pragma unroll
        for (int r = 0; r < 16; r++) {
            const float inv = 1.f / accL[r];
            const int row = (r & 3) + 8 * (r >> 2) + 4 * p;
            ob[(size_t)row * 64 + c]      = (bf16)(accO[0][r] * inv);
            ob[(size_t)row * 64 + 32 + c] = (bf16)(accO[1][r] * inv);
        }
    }
}

extern "C" void kernel_launch(void* const* d_in, const int* in_sizes, int n_in,
                              void* d_out, int out_size, void* d_ws, size_t ws_size,
                              hipStream_t stream) {
    const float* q     = (const float*)d_in[0];
    const float* gamma = (const float*)d_in[3];
    const float* beta  = (const float*)d_in[4];
    const float* Wq    = (const float*)d_in[5];
    const float* bq    = (const float*)d_in[6];
    const float* Wk    = (const float*)d_in[7];
    const float* bk    = (const float*)d_in[8];
    const float* Wv    = (const float*)d_in[9];
    const float* bv    = (const float*)d_in[10];
    const float* Wo    = (const float*)d_in[11];
    const float* bo    = (const float*)d_in[12];
    float* out = (float*)d_out;

    char* ws = (char*)d_ws;
    bf16* h     = (bf16*)(ws);                          // 8 MB
    bf16* WcatT = (bf16*)(ws + (8u << 20));             // 6 MB  [3072][1024]
    bf16* WoT   = (bf16*)(ws + (14u << 20));            // 2 MB  [1024][1024]
    bf16* qkv   = (bf16*)(ws + (16u << 20));            // 24 MB [4096][3072] (Q,K used)
    bf16* Obuf  = (bf16*)(ws + (40u << 20));            // 8 MB  [B][H][T][64]
    bf16* Vtb   = (bf16*)(ws + (48u << 20));            // 8 MB  [B][H][64][T]

    prep_kernel<<<8192, 256, 0, stream>>>(q, gamma, beta, h,
                                          Wq, Wk, Wv, Wo,
                                          WcatT, WcatT + (size_t)1024 * 1024,
                                          WcatT + (size_t)2048 * 1024, WoT);

    gemm0_kernel<<<dim3(24, 32), 256, 0, stream>>>(h, WcatT, qkv, bq, bk, bv, Vtb);

    attn_kernel<<<512, 512, 0, stream>>>(qkv, Vtb, Obuf);

    gemm1_kernel<<<dim3(8, 32), 256, 0, stream>>>(Obuf, WoT, out, bo, q);
}